// Round 13
// baseline (218.828 us; speedup 1.0000x reference)
//
#include <hip/hip_runtime.h>
#include <hip/hip_bf16.h>
#include <math.h>

// Problem constants
#define BB 4
#define CIN 64
#define CH 32
#define HH 64
#define WW 64
#define NN 4096           // H*W
#define MCH 4
#define NQCH 32           // q-chunks for column stats (chunk = 128 queries)
#define LOG2E 1.4426950408889634f
#define L2_10K 13.287712379549449f   // log2(10000)

// ws layout (floats). End = 2,278,400 floats = 8.69 MiB (ws >= 10.16 MiB proven).
// Temporal aliasing: CPSUM (k2a->k2b) and XA/XB (k4..k6) alias T8's region;
// T8 live only k3a->k3b, written after k2b, dead before k4.
#define Q4_OFF     1024       // 65536  (Q pre-scaled by LOG2E)
#define K4_OFF     66560      // 65536
#define CV_OFF     132096     // 16384  (c' in log2 domain)
#define RMAP_OFF   148480     // 16384
#define CMAPF_OFF  164864     // 16384
#define T8_OFF     181248     // 2097152 (16 chunks x 8 per query)
#define CPSUM_OFF  181248     // 524288 (aliases T8 head; dead before k3a)
#define XA_OFF     181248     // 524288 (aliases T8; written k4, after k3b)
#define XB_OFF     705536     // 524288 (aliases T8; written k5)

// out layout (FLOAT32 elements): x | out | corrected_map
#define OUT_X_OFF   0
#define OUT_O_OFF   524288
#define OUT_CM_OFF  540672

// compare-exchange (ascending)
#define CE(x, y) { float ce_lo = fminf(x, y); y = fmaxf(x, y); x = ce_lo; }

__device__ __forceinline__ float bilin32(const float* src, int b, int y, int x) {
    float sy = 0.5f * y - 0.25f;
    float sx = 0.5f * x - 0.25f;
    float fy0 = floorf(sy), fx0 = floorf(sx);
    int y0 = (int)fy0, x0 = (int)fx0;
    float fy = sy - fy0, fx = sx - fx0;
    int y0c = min(max(y0, 0), 31), y1c = min(max(y0 + 1, 0), 31);
    int x0c = min(max(x0, 0), 31), x1c = min(max(x0 + 1, 0), 31);
    const float* p = src + b * 1024;
    float v00 = p[y0c * 32 + x0c], v01 = p[y0c * 32 + x1c];
    float v10 = p[y1c * 32 + x0c], v11 = p[y1c * 32 + x1c];
    float v0 = v00 + fx * (v01 - v00);
    float v1 = v10 + fx * (v11 - v10);
    return v0 + fy * (v1 - v0);
}

// K1 v2: Q/K projections, pos table fused in-block, channel-split 16x4.
// 512-thread blocks, 32 queries/block -> grid = B*N/32 = 512 (4096 waves).
__global__ __launch_bounds__(512) void k1_qk(
        const float* __restrict__ fq, const float* __restrict__ fk,
        const float* __restrict__ wq, const float* __restrict__ wk,
        float* __restrict__ Q4, float* __restrict__ K4) {
    __shared__ float wqs[256], wks[256];
    __shared__ float pp[1024];            // [4 groups][4 m][64 coord]
    __shared__ float red[512][9];
    int tid = threadIdx.x;
    if (tid < 256) { wqs[tid] = wq[tid]; wks[tid] = wk[tid]; }
    __syncthreads();

    if (tid < 64) {   // pos table for coordinate t = tid (exact)
        float coord = (float)(tid + 1);
        float qy[4] = {0,0,0,0}, qx[4] = {0,0,0,0}, ky[4] = {0,0,0,0}, kx[4] = {0,0,0,0};
        for (int c = 0; c < 32; ++c) {
            float e = (2.0f * (float)(c >> 1)) * (1.0f / 32.0f);
            float ang = coord * exp2f(-e * L2_10K);
            float pr = (c & 1) ? cosf(ang) : sinf(ang);
            #pragma unroll
            for (int m = 0; m < 4; ++m) {
                qy[m] += wqs[m * 64 + c] * pr;
                qx[m] += wqs[m * 64 + 32 + c] * pr;
                ky[m] += wks[m * 64 + c] * pr;
                kx[m] += wks[m * 64 + 32 + c] * pr;
            }
        }
        #pragma unroll
        for (int m = 0; m < 4; ++m) {
            pp[0 * 256 + m * 64 + tid] = qy[m];
            pp[1 * 256 + m * 64 + tid] = qx[m];
            pp[2 * 256 + m * 64 + tid] = ky[m];
            pp[3 * 256 + m * 64 + tid] = kx[m];
        }
    }

    int qi = tid & 31, g = tid >> 5;      // g = 0..15, 4 channels each
    int gid = blockIdx.x * 32 + qi;
    int b = gid >> 12, hw = gid & 4095;
    const float* fqb = fq + (size_t)b * CIN * NN + hw;
    const float* fkb = fk + (size_t)b * CIN * NN + hw;
    float aq[4] = {0,0,0,0}, ak[4] = {0,0,0,0};
    int c0 = g * 4;
    #pragma unroll
    for (int c = c0; c < c0 + 4; ++c) {
        float vq = fqb[c * NN];
        float vk = fkb[c * NN];
        #pragma unroll
        for (int m = 0; m < 4; ++m) {
            aq[m] += wqs[m * 64 + c] * vq;
            ak[m] += wks[m * 64 + c] * vk;
        }
    }
    #pragma unroll
    for (int m = 0; m < 4; ++m) { red[tid][m] = aq[m]; red[tid][4 + m] = ak[m]; }
    __syncthreads();
    if (tid < 32) {
        int y = hw >> 6, x = hw & 63;
        float q4[4], k4[4];
        #pragma unroll
        for (int m = 0; m < 4; ++m) {
            float sq = 0.0f, sk = 0.0f;
            #pragma unroll
            for (int j = 0; j < 16; ++j) {
                sq += red[tid + 32 * j][m];
                sk += red[tid + 32 * j][4 + m];
            }
            q4[m] = LOG2E * (sq + pp[0 * 256 + m * 64 + y] + pp[1 * 256 + m * 64 + x]);
            k4[m] = sk + pp[2 * 256 + m * 64 + y] + pp[3 * 256 + m * 64 + x];
        }
        ((float4*)Q4)[gid] = make_float4(q4[0], q4[1], q4[2], q4[3]);
        ((float4*)K4)[gid] = make_float4(k4[0], k4[1], k4[2], k4[3]);
    }
}

// K2a v2: per-(b, q-chunk of 128) column sum of 2^(q'.k), 1 key/thread.
// grid = B*32*16 = 2048 (8192 waves = 8/SIMD). Queries via uniform scalar loads.
__global__ __launch_bounds__(256) void k2a_colstats(
        const float* __restrict__ Q4, const float* __restrict__ K4,
        float* __restrict__ cpsum) {
    int blk = blockIdx.x;
    int kblk = blk & 15;  blk >>= 4;
    int qch  = blk & 31;  blk >>= 5;
    int b    = blk;
    int tid = threadIdx.x;
    const float4* Qg = (const float4*)Q4 + b * NN + qch * 128;  // uniform base
    int k0 = kblk * 256 + tid;
    float4 kv = ((const float4*)K4)[b * NN + k0];
    float s = 0.0f;
    #pragma unroll 8
    for (int i = 0; i < 128; ++i) {
        float4 q = Qg[i];   // uniform -> s_load broadcast
        float d = fmaf(q.x, kv.x, fmaf(q.y, kv.y, fmaf(q.z, kv.z, q.w * kv.w)));
        s += exp2f(d);
    }
    cpsum[(b * NQCH + qch) * NN + k0] = s;
}

// K2b: merge chunk sums -> c'[b][k] = LOG2E*(m_k_r - 1) - log2(colsum)
__global__ void k2b_cmerge(const float* __restrict__ cpsum,
                           const float* __restrict__ m_k, float* __restrict__ cvals) {
    int gid = blockIdx.x * 256 + threadIdx.x;  // B*N
    int b = gid >> 12, k = gid & 4095;
    float S = 0.0f;
    #pragma unroll
    for (int j = 0; j < NQCH; ++j) S += cpsum[(b * NQCH + j) * NN + k];
    float mk = bilin32(m_k, b, k >> 6, k & 63);
    cvals[gid] = LOG2E * (mk - 1.0f) - log2f(S);
}

// K3a v5: 8-wave blocks; wave-halves split each 256-key chunk (128 keys each),
// verified v4 batch loop body, round-10-verified LDS half-merge.
// grid = B*16(qg)*16(kc) = 1024 blocks x 512 thr = 8192 waves = 8/SIMD.
__global__ __launch_bounds__(512) void k3a_scan(
        const float* __restrict__ Q4, const float* __restrict__ K4,
        const float* __restrict__ cvals, float* __restrict__ t8) {
    __shared__ float sbuf[4][64][9];   // 9 KB
    int blk = blockIdx.x;
    int kc = blk & 15;  blk >>= 4;
    int g4 = blk & 15;  blk >>= 4;
    int b  = blk;
    int tid = threadIdx.x;
    int wave = tid >> 6, lane = tid & 63;
    int wsub = wave & 3, half = wave >> 2;
    int qrow = (g4 * 4 + wsub) * 64 + lane;
    float4 qv = ((const float4*)Q4)[b * NN + qrow];
    const float4* Kb = (const float4*)K4 + b * NN + kc * 256 + half * 128; // uniform
    const float* cb = cvals + b * NN + kc * 256 + half * 128;              // uniform

    float t0=-1e30f,t1=-1e30f,t2=-1e30f,t3=-1e30f;
    float t4=-1e30f,t5=-1e30f,t6=-1e30f,t7=-1e30f;   // ascending; t0 = 8th

    #pragma unroll 2
    for (int i0 = 0; i0 < 128; i0 += 8) {
        float4 k0 = Kb[i0 + 0]; float4 k1 = Kb[i0 + 1];
        float4 k2 = Kb[i0 + 2]; float4 k3 = Kb[i0 + 3];
        float4 k4 = Kb[i0 + 4]; float4 k5 = Kb[i0 + 5];
        float4 k6 = Kb[i0 + 6]; float4 k7 = Kb[i0 + 7];
        float s0 = fmaf(qv.x,k0.x, fmaf(qv.y,k0.y, fmaf(qv.z,k0.z, qv.w*k0.w))) + cb[i0+0];
        float s1 = fmaf(qv.x,k1.x, fmaf(qv.y,k1.y, fmaf(qv.z,k1.z, qv.w*k1.w))) + cb[i0+1];
        float s2 = fmaf(qv.x,k2.x, fmaf(qv.y,k2.y, fmaf(qv.z,k2.z, qv.w*k2.w))) + cb[i0+2];
        float s3 = fmaf(qv.x,k3.x, fmaf(qv.y,k3.y, fmaf(qv.z,k3.z, qv.w*k3.w))) + cb[i0+3];
        float s4 = fmaf(qv.x,k4.x, fmaf(qv.y,k4.y, fmaf(qv.z,k4.z, qv.w*k4.w))) + cb[i0+4];
        float s5 = fmaf(qv.x,k5.x, fmaf(qv.y,k5.y, fmaf(qv.z,k5.z, qv.w*k5.w))) + cb[i0+5];
        float s6 = fmaf(qv.x,k6.x, fmaf(qv.y,k6.y, fmaf(qv.z,k6.z, qv.w*k6.w))) + cb[i0+6];
        float s7 = fmaf(qv.x,k7.x, fmaf(qv.y,k7.y, fmaf(qv.z,k7.z, qv.w*k7.w))) + cb[i0+7];
        float bm = fmaxf(fmaxf(fmaxf(s0,s1), fmaxf(s2,s3)),
                         fmaxf(fmaxf(s4,s5), fmaxf(s6,s7)));
        if (bm > t0) {
            // Batcher odd-even mergesort, 8 elems ascending (19 CE)
            CE(s0,s1); CE(s2,s3); CE(s4,s5); CE(s6,s7);
            CE(s0,s2); CE(s1,s3); CE(s4,s6); CE(s5,s7);
            CE(s1,s2); CE(s5,s6);
            CE(s0,s4); CE(s1,s5); CE(s2,s6); CE(s3,s7);
            CE(s2,s4); CE(s3,s5);
            CE(s1,s2); CE(s3,s4); CE(s5,s6);
            // bitonic max-merge: top-8 of {t} u {s} (both ascending)
            t0 = fmaxf(t0, s7); t1 = fmaxf(t1, s6); t2 = fmaxf(t2, s5); t3 = fmaxf(t3, s4);
            t4 = fmaxf(t4, s3); t5 = fmaxf(t5, s2); t6 = fmaxf(t6, s1); t7 = fmaxf(t7, s0);
            // result is bitonic -> 12-CE bitonic sort (ascending)
            CE(t0,t4); CE(t1,t5); CE(t2,t6); CE(t3,t7);
            CE(t0,t2); CE(t1,t3); CE(t4,t6); CE(t5,t7);
            CE(t0,t1); CE(t2,t3); CE(t4,t5); CE(t6,t7);
        }
    }
    // merge the two halves (round-10-verified pattern)
    if (half == 1) {
        float* sb_ = &sbuf[wsub][lane][0];
        sb_[0] = t0; sb_[1] = t1; sb_[2] = t2; sb_[3] = t3;
        sb_[4] = t4; sb_[5] = t5; sb_[6] = t6; sb_[7] = t7;
    }
    __syncthreads();
    if (half == 0) {
        const float* sb_ = &sbuf[wsub][lane][0];
        float f0 = fmaxf(t0, sb_[7]);
        float f1 = fmaxf(t1, sb_[6]);
        float f2 = fmaxf(t2, sb_[5]);
        float f3 = fmaxf(t3, sb_[4]);
        float f4 = fmaxf(t4, sb_[3]);
        float f5 = fmaxf(t5, sb_[2]);
        float f6 = fmaxf(t6, sb_[1]);
        float f7 = fmaxf(t7, sb_[0]);
        float* o = t8 + ((size_t)(b * NN + qrow)) * 128 + kc * 8;
        o[0] = f0; o[1] = f1; o[2] = f2; o[3] = f3;
        o[4] = f4; o[5] = f5; o[6] = f6; o[7] = f7;
    }
}

// K3b: merge 16 chunk-top8s (128 candidates) -> global top-8 -> cm/rmap.
__global__ void k3b_merge(const float* __restrict__ t8, const float* __restrict__ mapin,
                          float* __restrict__ rmap, float* __restrict__ cmapf,
                          float* __restrict__ outp) {
    int tid = threadIdx.x;
    int qid = blockIdx.x * 4 + (tid >> 6);   // 0 .. B*N-1
    int lane = tid & 63;
    float va = t8[(size_t)qid * 128 + lane];
    float vb = t8[(size_t)qid * 128 + 64 + lane];
    float hi = fmaxf(va, vb), lo = fminf(va, vb);
    float sm = 0.0f;
    #pragma unroll
    for (int r = 0; r < 8; ++r) {
        float m = hi;
        int ln = lane;
        #pragma unroll
        for (int off = 32; off >= 1; off >>= 1) {
            float om = __shfl_xor(m, off);
            int ol = __shfl_xor(ln, off);
            if (om > m || (om == m && ol < ln)) { m = om; ln = ol; }
        }
        sm += exp2f(m);
        if (lane == ln) { hi = lo; lo = -1e30f; }
    }
    if (lane == 0) {
        float cmv = sm * 0.125f;
        int b = qid >> 12, hw = qid & 4095;
        float mr = bilin32(mapin, b, hw >> 6, hw & 63);
        float cm = cmv * mr + mr;
        float rm = 1.0f / (1.0f + __expf(cm));
        rmap[qid] = rm;
        cmapf[qid] = cm;
        outp[OUT_CM_OFF + qid] = cm;
    }
}

// K4: x1 = conv1x1(rmap*f, w_in) + b_in. og-split 8 -> grid 512
__global__ void k4_conv1(const float* __restrict__ f, const float* __restrict__ rmap,
                         const float* __restrict__ w_in, const float* __restrict__ b_in,
                         float* __restrict__ xout) {
    __shared__ float ws_[1024];
    __shared__ float bs[32];
    int tid = threadIdx.x;
    for (int i = tid; i < 1024; i += 256) ws_[i] = w_in[i];
    if (tid < 32) bs[tid] = b_in[tid];
    __syncthreads();
    int gid = blockIdx.x * 256 + tid;      // b(2b) og(3b) hw(12b)
    int hw = gid & 4095;
    int og = (gid >> 12) & 7;
    int b  = gid >> 15;
    float rm = rmap[b * NN + hw];
    float acc[4];
    #pragma unroll
    for (int j = 0; j < 4; ++j) acc[j] = bs[og * 4 + j];
    const float* fb = f + (size_t)b * CH * NN + hw;
    for (int i = 0; i < 32; ++i) {
        float v = fb[i * NN] * rm;
        #pragma unroll
        for (int j = 0; j < 4; ++j) acc[j] += ws_[(og * 4 + j) * 32 + i] * v;
    }
    float* xo = xout + (size_t)b * CH * NN + (og * 4) * NN + hw;
    #pragma unroll
    for (int j = 0; j < 4; ++j) xo[j * NN] = acc[j];
}

// K5: 3x3 conv 32->32 (+bias, relu). og-split 8 -> grid = b*ty*tx*og = 512
__global__ void k5_conv3(const float* __restrict__ xin, const float* __restrict__ w,
                         const float* __restrict__ bias, float* __restrict__ xout,
                         float* __restrict__ outx) {
    __shared__ float tile[32][324];   // 18x18 per channel
    __shared__ float wsm[1152];       // 4 o x 32 i x 9
    __shared__ float bsm[4];
    int blk = blockIdx.x;
    int og = blk & 7;  blk >>= 3;
    int tx = blk & 3;  blk >>= 2;
    int ty = blk & 3;  blk >>= 2;
    int b  = blk;
    int tid = threadIdx.x;
    for (int i = tid; i < 1152; i += 256) wsm[i] = w[og * 1152 + i];
    if (tid < 4) bsm[tid] = bias[og * 4 + tid];
    int y0 = ty * 16 - 1, x0 = tx * 16 - 1;
    for (int i = tid; i < 32 * 324; i += 256) {
        int c = i / 324, r = i % 324;
        int yy = r / 18, xx = r % 18;
        int gy = y0 + yy, gx = x0 + xx;
        float v = 0.0f;
        if (gy >= 0 && gy < 64 && gx >= 0 && gx < 64)
            v = xin[((size_t)b * CH + c) * NN + gy * 64 + gx];
        tile[c][r] = v;
    }
    __syncthreads();
    int py = tid >> 4, px = tid & 15;
    float acc[4];
    #pragma unroll
    for (int j = 0; j < 4; ++j) acc[j] = bsm[j];
    for (int i = 0; i < 32; ++i) {
        const float* tr = &tile[i][py * 18 + px];
        float v00 = tr[0],  v01 = tr[1],  v02 = tr[2];
        float v10 = tr[18], v11 = tr[19], v12 = tr[20];
        float v20 = tr[36], v21 = tr[37], v22 = tr[38];
        #pragma unroll
        for (int j = 0; j < 4; ++j) {
            const float* wj = &wsm[j * 288 + i * 9];
            acc[j] += v00 * wj[0] + v01 * wj[1] + v02 * wj[2]
                    + v10 * wj[3] + v11 * wj[4] + v12 * wj[5]
                    + v20 * wj[6] + v21 * wj[7] + v22 * wj[8];
        }
    }
    size_t base = (size_t)b * CH * NN + (size_t)(og * 4) * NN
                + (ty * 16 + py) * 64 + tx * 16 + px;
    #pragma unroll
    for (int j = 0; j < 4; ++j) {
        float r_ = fmaxf(acc[j], 0.0f);
        xout[base + j * NN] = r_;
        if (outx) outx[base + j * NN] = r_;
    }
}

// K6: final 3x3 conv 32->1 + b_out + corrected_map. channel-split 4x8, grid 256
__global__ void k6_convout(const float* __restrict__ xin, const float* __restrict__ w_out,
                           const float* __restrict__ b_out, const float* __restrict__ cmapf,
                           float* __restrict__ outp) {
    __shared__ float wsm[288];
    __shared__ float red[256];
    int tid = threadIdx.x;
    for (int i = tid; i < 288; i += 256) wsm[i] = w_out[i];
    int pxi = tid & 63, g = tid >> 6;
    int gid = blockIdx.x * 64 + pxi;   // B*N over 256 blocks
    int b = gid >> 12, hw = gid & 4095;
    int y = hw >> 6, x = hw & 63;
    __syncthreads();
    float acc = 0.0f;
    int c0 = g * 8;
    for (int i = c0; i < c0 + 8; ++i) {
        const float* xi = xin + ((size_t)b * CH + i) * NN;
        #pragma unroll
        for (int ky = 0; ky < 3; ++ky) {
            int gy = y + ky - 1;
            if (gy < 0 || gy > 63) continue;
            #pragma unroll
            for (int kx = 0; kx < 3; ++kx) {
                int gx = x + kx - 1;
                if (gx < 0 || gx > 63) continue;
                acc += xi[gy * 64 + gx] * wsm[i * 9 + ky * 3 + kx];
            }
        }
    }
    red[tid] = acc;
    __syncthreads();
    if (tid < 64) {
        float a = red[tid] + red[tid + 64] + red[tid + 128] + red[tid + 192]
                + b_out[0] + cmapf[gid];
        outp[OUT_O_OFF + gid] = a;
    }
}

extern "C" void kernel_launch(void* const* d_in, const int* in_sizes, int n_in,
                              void* d_out, int out_size, void* d_ws, size_t ws_size,
                              hipStream_t stream) {
    const float* f     = (const float*)d_in[0];
    const float* mapin = (const float*)d_in[1];
    const float* f_q   = (const float*)d_in[2];
    const float* f_k   = (const float*)d_in[3];
    const float* m_k   = (const float*)d_in[4];
    const float* wq    = (const float*)d_in[5];
    const float* wk    = (const float*)d_in[6];
    const float* w_in  = (const float*)d_in[7];
    const float* b_in  = (const float*)d_in[8];
    const float* w_mid = (const float*)d_in[9];
    const float* b_mid = (const float*)d_in[10];
    const float* w_out = (const float*)d_in[11];
    const float* b_out = (const float*)d_in[12];
    float* outp = (float*)d_out;
    float* ws = (float*)d_ws;

    float* Q4    = ws + Q4_OFF;
    float* K4    = ws + K4_OFF;
    float* CV    = ws + CV_OFF;
    float* CPSUM = ws + CPSUM_OFF;
    float* RMAP  = ws + RMAP_OFF;
    float* CMAPF = ws + CMAPF_OFF;
    float* T8    = ws + T8_OFF;
    float* XA    = ws + XA_OFF;
    float* XB    = ws + XB_OFF;

    k1_qk<<<512, 512, 0, stream>>>(f_q, f_k, wq, wk, Q4, K4);
    k2a_colstats<<<BB * NQCH * 16, 256, 0, stream>>>(Q4, K4, CPSUM);
    k2b_cmerge<<<64, 256, 0, stream>>>(CPSUM, m_k, CV);
    k3a_scan<<<BB * 16 * 16, 512, 0, stream>>>(Q4, K4, CV, T8);
    k3b_merge<<<BB * NN / 4, 256, 0, stream>>>(T8, mapin, RMAP, CMAPF, outp);
    k4_conv1<<<512, 256, 0, stream>>>(f, RMAP, w_in, b_in, XA);
    k5_conv3<<<512, 256, 0, stream>>>(XA, w_mid + 0 * 9216, b_mid + 0 * 32, XB, (float*)0);
    k5_conv3<<<512, 256, 0, stream>>>(XB, w_mid + 1 * 9216, b_mid + 1 * 32, XA, (float*)0);
    k5_conv3<<<512, 256, 0, stream>>>(XA, w_mid + 2 * 9216, b_mid + 2 * 32, XB, outp + OUT_X_OFF);
    k6_convout<<<256, 256, 0, stream>>>(XB, w_out, b_out, CMAPF, outp);
}